// Round 11
// baseline (112.148 us; speedup 1.0000x reference)
//
#include <hip/hip_runtime.h>
#include <hip/hip_bf16.h>

#define N0C 100000
#define N1C 50000
#define N2C 25000

typedef _Float16 f16;
typedef _Float16 f16x2 __attribute__((ext_vector_type(2)));
typedef _Float16 f16x4 __attribute__((ext_vector_type(4)));
typedef _Float16 f16x8 __attribute__((ext_vector_type(8)));
typedef float f32x16 __attribute__((ext_vector_type(16)));

typedef const __attribute__((address_space(1))) unsigned int guint;
typedef __attribute__((address_space(3))) unsigned int luint;
__device__ __forceinline__ void gload16(const void* g, void* l) {
    __builtin_amdgcn_global_load_lds((guint*)g, (luint*)l, 16, 0, 0);
}

// ---------------------------------------------------------------- prep1 -----
__global__ void prep1_kernel(const float* __restrict__ Ws1, const float* __restrict__ Wd1,
                             const float* __restrict__ as1, const float* __restrict__ ad1,
                             const float* __restrict__ Ws2, const float* __restrict__ Wd2,
                             const float* __restrict__ as2, const float* __restrict__ ad2,
                             const float* __restrict__ b1, const float* __restrict__ g1,
                             const float* __restrict__ beta1, const float* __restrict__ m1,
                             const float* __restrict__ v1,
                             float* __restrict__ e1, float* __restrict__ e2,
                             float* __restrict__ bns, float* __restrict__ bnt) {
    int k = blockIdx.x, lane = threadIdx.x;
    float s0 = 0, s1 = 0, d0 = 0, d1 = 0, t0 = 0, t1 = 0;
    for (int c = lane; c < 128; c += 64) {
        s0 += Ws1[k * 256 + c] * as1[c];
        s1 += Ws1[k * 256 + 128 + c] * as1[128 + c];
        d0 += Wd1[k * 256 + c] * ad1[c];
        d1 += Wd1[k * 256 + 128 + c] * ad1[128 + c];
        t0 += Ws2[k * 128 + c] * as2[c];
        t1 += Wd2[k * 128 + c] * ad2[c];
    }
    for (int d = 1; d < 64; d <<= 1) {
        s0 += __shfl_xor(s0, d); s1 += __shfl_xor(s1, d);
        d0 += __shfl_xor(d0, d); d1 += __shfl_xor(d1, d);
        t0 += __shfl_xor(t0, d); t1 += __shfl_xor(t1, d);
    }
    if (lane == 0) {
        e1[k * 4 + 0] = s0; e1[k * 4 + 1] = s1; e1[k * 4 + 2] = d0; e1[k * 4 + 3] = d1;
        e2[k * 2 + 0] = t0; e2[k * 2 + 1] = t1;
        float sc = g1[k] * rsqrtf(v1[k] + 1e-5f);
        bns[k] = sc;
        bnt[k] = (b1[k] - m1[k]) * sc + beta1[k];
    }
}

// ---------------------------------------------------------------- prep2 -----
// bfl1: [9 nt][16 kb][64 lane][8 j]; bfl2: [5 nt][16 kb][64 lane][8 j]
// element (nt,kb,lane,j): n = nt*32 + (lane&31), k = kb*16 + (lane>>5)*8 + j
__global__ void prep2_kernel(const float* __restrict__ Ws1, const float* __restrict__ Ws2,
                             const float* __restrict__ e1, const float* __restrict__ e2,
                             f16* __restrict__ bfl1, f16* __restrict__ bfl2) {
    int i = blockIdx.x * 256 + threadIdx.x;
    if (i < 73728) {
        int j = i & 7, lane = (i >> 3) & 63, kb = (i >> 9) & 15, nt = i >> 13;
        int c = lane & 31, hi = lane >> 5;
        int k = kb * 16 + hi * 8 + j;
        float v;
        if (nt < 8) v = Ws1[k * 256 + nt * 32 + c];
        else v = (c < 4) ? e1[k * 4 + c] : 0.f;
        bfl1[i] = (f16)v;
    } else {
        int i2 = i - 73728;
        if (i2 < 40960) {
            int j = i2 & 7, lane = (i2 >> 3) & 63, kb = (i2 >> 9) & 15, nt = i2 >> 13;
            int c = lane & 31, hi = lane >> 5;
            int k = kb * 16 + hi * 8 + j;
            float v;
            if (nt < 4) v = Ws2[k * 128 + nt * 32 + c];
            else v = (c < 2) ? e2[k * 2 + c] : 0.f;
            bfl2[i2] = (f16)v;
        }
    }
}

// ---------------------------------------------------------------- gemm1 -----
// High-occupancy K-split (R8 fixed). Block = 640 thr = 5 ntl x 2 khalf;
// grid (2, 3125): blockIdx.x = nt-half (FAST index -> both halves of a row
// tile co-resident, shared x reads L2-hot), blockIdx.y = row tile (32 rows).
// nt = half*5 + ntl; nt 0..8 real (8 = attention pad), nt 9 dummy.
// A: staged once to kb-XOR-swizzled fragment-linear LDS (16 KB). K-half
// partials summed via [r][ntl][lane] f32 LDS buffer (20 KB, reuses smA).
// Combined regs ~48-56 (<64) -> 8 waves/SIMD eligible; 3 blocks/CU by LDS.
__global__ __launch_bounds__(640, 8) void gemm1_kernel(
    const float* __restrict__ x, const f16* __restrict__ bfl,
    f16* __restrict__ hs, float* __restrict__ as_out, float* __restrict__ ad_out) {
    __shared__ __align__(16) unsigned char smA[20480];
    const int t = threadIdx.x;
    const int wave = t >> 6, lane = t & 63;
    const int ntl = wave >> 1, kh = wave & 1;
    const int nt0 = blockIdx.x * 5 + ntl;        // 0..9
    const int nt = nt0 > 8 ? 8 : nt0;            // clamp dummy to a valid load
    const int col = lane & 31, hi = lane >> 5;
    const int r0 = blockIdx.y * 32;              // 3125*32 = 100000 exact

    // stage A: 512 threads; thread -> row r = t>>4, float4 q = (t&15)+16p.
    // lanes 0-15 read 256B contiguous of one row (full lines). Frag (kb,hp,hf)
    // written to slot (kb*64+hp*32+r)*16 ^ ((kb&7)<<4)  [2-way on write].
    if (t < 512) {
        int r = t >> 4, s = t & 15;
        const float4* src = (const float4*)(x + (size_t)(r0 + r) * 256) + s;
#pragma unroll
        for (int p = 0; p < 4; p++) {
            float4 v = src[16 * p];
            int q = s + 16 * p;
            int kb = q >> 2, hp = (q >> 1) & 1, hf = q & 1;
            f16x4 h4 = {(f16)v.x, (f16)v.y, (f16)v.z, (f16)v.w};
            int byt = (((kb * 64 + hp * 32 + r) * 16) ^ ((kb & 7) << 4)) + hf * 8;
            *(f16x4*)(smA + byt) = h4;
        }
    }
    __syncthreads();

    // K-half compute: b-frags in 2 groups of 4 (keeps live regs ~48)
    f32x16 acc = {};
#pragma unroll
    for (int g = 0; g < 2; g++) {
        f16x8 b[4];
#pragma unroll
        for (int i = 0; i < 4; i++)
            b[i] = *(const f16x8*)(bfl + ((size_t)(nt * 16 + kh * 8 + g * 4 + i) * 64 + lane) * 8);
#pragma unroll
        for (int i = 0; i < 4; i++) {
            int kb = kh * 8 + g * 4 + i;
            f16x8 af = *(const f16x8*)(smA + (((kb * 64 + hi * 32 + col) * 16) ^ ((kb & 7) << 4)));
            acc = __builtin_amdgcn_mfma_f32_32x32x16_f16(af, b[i], acc, 0, 0, 0);
        }
    }
    __syncthreads();

    // K-half reduce through LDS: [r][ntl][lane] f32 (stride-4B, ~2-way)
    float* rb = (float*)smA;
    if (kh == 1) {
#pragma unroll
        for (int r = 0; r < 16; r++) rb[(r * 5 + ntl) * 64 + lane] = acc[r];
    }
    __syncthreads();
    if (kh == 0 && nt0 <= 8) {
        if (nt0 < 8) {
#pragma unroll
            for (int r = 0; r < 16; r++) {
                int grow = r0 + (r & 3) + 8 * (r >> 2) + 4 * hi;
                hs[(size_t)grow * 256 + nt0 * 32 + col] =
                    (f16)(acc[r] + rb[(r * 5 + ntl) * 64 + lane]);
            }
        } else {
#pragma unroll
            for (int r = 0; r < 16; r++) {
                int grow = r0 + (r & 3) + 8 * (r >> 2) + 4 * hi;
                float v = acc[r] + rb[(r * 5 + ntl) * 64 + lane];
                if (col < 2) {
                    as_out[grow * 2 + col] = v;
                } else if (col < 4) {
                    if (grow < N1C) ad_out[grow * 2 + (col - 2)] = v;
                }
            }
        }
    }
}

// ---------------------------------------------------------------- gemm2 -----
// R10's 2-phase skeleton (unchanged). A (f16) via global_load_lds with
// per-lane fragment-linear SOURCE; 8 A + 10 B chunks per step.
__global__ __launch_bounds__(512, 4) void gemm2_kernel(
    const f16* __restrict__ h, const f16* __restrict__ bfl,
    f16* __restrict__ hs2, float* __restrict__ as_out, float* __restrict__ ad_out) {
    __shared__ __align__(16) unsigned char smA[2][8192];
    __shared__ __align__(16) unsigned char smB[2][10240];
    const int t = threadIdx.x;
    const int wave = t >> 6, lane = t & 63;
    const int wr = wave & 3, wg = wave >> 2;
    const int col = lane & 31, hi = lane >> 5;
    const int r0 = blockIdx.x * 128;

    const int wrA = wave >> 1, kbA = wave & 1;
    int arowg = r0 + wrA * 32 + col;
    if (arowg > N1C - 1) arowg = N1C - 1;
    const f16* asrc = h + (size_t)arowg * 256 + kbA * 16 + hi * 8;

    gload16(asrc, smA[0] + wave * 1024 + lane * 16);
    for (int c = wave; c < 10; c += 8) {
        int nt = c >> 1, kbl = c & 1;
        gload16(bfl + ((size_t)(nt * 16 + kbl) * 64 + lane) * 8, smB[0] + c * 1024 + lane * 16);
    }
    __syncthreads();

    f32x16 acc[3] = {};
    for (int ch = 0; ch < 8; ch++) {
        const int cur = ch & 1, nxt = cur ^ 1;
        const bool pre = ch < 7;
        if (pre) {
            gload16(asrc + (ch + 1) * 32, smA[nxt] + wave * 1024 + lane * 16);
            for (int c = wave; c < 10; c += 8) {
                int nt = c >> 1, kbl = c & 1;
                gload16(bfl + ((size_t)(nt * 16 + (ch + 1) * 2 + kbl) * 64 + lane) * 8,
                        smB[nxt] + c * 1024 + lane * 16);
            }
        }
#pragma unroll
        for (int kb = 0; kb < 2; kb++) {
            f16x8 af = *(const f16x8*)(smA[cur] + ((wr * 2 + kb) * 64 + lane) * 16);
            if (wg == 0) {
#pragma unroll
                for (int j = 0; j < 3; j++) {
                    f16x8 bf = *(const f16x8*)(smB[cur] + (j * 2 + kb) * 1024 + lane * 16);
                    acc[j] = __builtin_amdgcn_mfma_f32_32x32x16_f16(af, bf, acc[j], 0, 0, 0);
                }
            } else {
#pragma unroll
                for (int j = 0; j < 2; j++) {
                    f16x8 bf = *(const f16x8*)(smB[cur] + ((3 + j) * 2 + kb) * 1024 + lane * 16);
                    acc[j] = __builtin_amdgcn_mfma_f32_32x32x16_f16(af, bf, acc[j], 0, 0, 0);
                }
            }
        }
        __syncthreads();
    }

    const int rbase = r0 + wr * 32 + 4 * hi;
    if (wg == 0) {
#pragma unroll
        for (int j = 0; j < 3; j++)
#pragma unroll
            for (int r = 0; r < 16; r++) {
                int grow = rbase + (r & 3) + 8 * (r >> 2);
                if (grow < N1C) hs2[(size_t)grow * 128 + j * 32 + col] = (f16)acc[j][r];
            }
    } else {
#pragma unroll
        for (int r = 0; r < 16; r++) {
            int grow = rbase + (r & 3) + 8 * (r >> 2);
            if (grow < N1C) hs2[(size_t)grow * 128 + 3 * 32 + col] = (f16)acc[0][r];
        }
#pragma unroll
        for (int r = 0; r < 16; r++) {
            int grow = rbase + (r & 3) + 8 * (r >> 2);
            float v = acc[1][r];
            if (col == 0) {
                if (grow < N1C) as_out[grow] = v;
            } else if (col == 1) {
                if (grow < N2C) ad_out[grow] = v;
            }
        }
    }
}

// ---------------------------------------------------------------- agg1 ------
__global__ void agg1_kernel(const int* __restrict__ col1, const int* __restrict__ t1,
                            const int* __restrict__ timep, const int* __restrict__ intervalp,
                            const float* __restrict__ a_s, const float* __restrict__ a_d,
                            const f16* __restrict__ hs,
                            const float* __restrict__ bns, const float* __restrict__ bnt,
                            f16* __restrict__ h) {
    int wid = (blockIdx.x * blockDim.x + threadIdx.x) >> 6;
    if (wid >= N1C) return;
    int lane = threadIdx.x & 63;
    int T = timep[0], I = intervalp[0];
    int j = lane & 15;
    int c = col1[wid * 16 + j];
    int tv = t1[wid * 16 + j];
    bool mk = (tv >= T) && (tv < T + I);
    float e0 = -INFINITY, e1 = -INFINITY;
    if (mk) {
        float s0 = a_s[c * 2 + 0] + a_d[wid * 2 + 0];
        float s1 = a_s[c * 2 + 1] + a_d[wid * 2 + 1];
        e0 = s0 > 0.f ? s0 : 0.2f * s0;
        e1 = s1 > 0.f ? s1 : 0.2f * s1;
    }
    float m0 = e0, m1 = e1;
#pragma unroll
    for (int d = 1; d < 16; d <<= 1) {
        m0 = fmaxf(m0, __shfl_xor(m0, d));
        m1 = fmaxf(m1, __shfl_xor(m1, d));
    }
    float ex0 = mk ? __expf(e0 - m0) : 0.f;
    float ex1 = mk ? __expf(e1 - m1) : 0.f;
    float s0 = ex0, s1 = ex1;
#pragma unroll
    for (int d = 1; d < 16; d <<= 1) {
        s0 += __shfl_xor(s0, d);
        s1 += __shfl_xor(s1, d);
    }
    float r0 = 1.f / fmaxf(s0, 1e-16f);
    float r1 = 1.f / fmaxf(s1, 1e-16f);
    unsigned long long mb = __ballot(mk) & 0xFFFFull;
    int head = lane >> 5;
    float rden = head ? r1 : r0;
    float acc0 = 0.f, acc1 = 0.f, acc2 = 0.f, acc3 = 0.f;
    while (mb) {
        int jj = __builtin_ctzll(mb);
        mb &= mb - 1;
        int cj = __shfl(c, jj);
        float w0 = __shfl(ex0, jj), w1 = __shfl(ex1, jj);
        float w = (head ? w1 : w0) * rden;
        f16x4 v = *(const f16x4*)(hs + (size_t)cj * 256 + lane * 4);
        acc0 += w * (float)v[0];
        acc1 += w * (float)v[1];
        acc2 += w * (float)v[2];
        acc3 += w * (float)v[3];
    }
    int cb = lane * 4;
    float4 sc = *(const float4*)(bns + cb);
    float4 sh = *(const float4*)(bnt + cb);
    float o0 = acc0 * sc.x + sh.x; o0 = o0 > 0.f ? o0 : 0.01f * o0;
    float o1 = acc1 * sc.y + sh.y; o1 = o1 > 0.f ? o1 : 0.01f * o1;
    float o2 = acc2 * sc.z + sh.z; o2 = o2 > 0.f ? o2 : 0.01f * o2;
    float o3 = acc3 * sc.w + sh.w; o3 = o3 > 0.f ? o3 : 0.01f * o3;
    f16x4 ov = {(f16)o0, (f16)o1, (f16)o2, (f16)o3};
    *(f16x4*)(h + (size_t)wid * 256 + cb) = ov;
}

// ---------------------------------------------------------------- agg2 ------
__global__ void agg2_kernel(const int* __restrict__ col2, const int* __restrict__ t2,
                            const int* __restrict__ timep, const int* __restrict__ intervalp,
                            const float* __restrict__ a_s, const float* __restrict__ a_d,
                            const f16* __restrict__ hs2,
                            const float* __restrict__ b2, float* __restrict__ out) {
    int wid = (blockIdx.x * blockDim.x + threadIdx.x) >> 6;
    if (wid >= N2C) return;
    int lane = threadIdx.x & 63;
    int T = timep[0], I = intervalp[0];
    int j = lane & 15;
    int c = col2[wid * 16 + j];
    int tv = t2[wid * 16 + j];
    bool mk = (tv >= T) && (tv < T + I);
    float e = -INFINITY;
    if (mk) {
        float s = a_s[c] + a_d[wid];
        e = s > 0.f ? s : 0.2f * s;
    }
    float m = e;
#pragma unroll
    for (int d = 1; d < 16; d <<= 1) m = fmaxf(m, __shfl_xor(m, d));
    float ex = mk ? __expf(e - m) : 0.f;
    float s = ex;
#pragma unroll
    for (int d = 1; d < 16; d <<= 1) s += __shfl_xor(s, d);
    float r = 1.f / fmaxf(s, 1e-16f);
    unsigned long long mb = __ballot(mk) & 0xFFFFull;
    float acc0 = 0.f, acc1 = 0.f;
    while (mb) {
        int jj = __builtin_ctzll(mb);
        mb &= mb - 1;
        int cj = __shfl(c, jj);
        float w = __shfl(ex, jj) * r;
        f16x2 v = *(const f16x2*)(hs2 + (size_t)cj * 128 + lane * 2);
        acc0 += w * (float)v[0];
        acc1 += w * (float)v[1];
    }
    float2 o = make_float2(acc0 + b2[lane * 2], acc1 + b2[lane * 2 + 1]);
    *(float2*)(out + (size_t)wid * 128 + lane * 2) = o;
}

// ---------------------------------------------------------------- launch ----
extern "C" void kernel_launch(void* const* d_in, const int* in_sizes, int n_in,
                              void* d_out, int out_size, void* d_ws, size_t ws_size,
                              hipStream_t stream) {
    const float* x = (const float*)d_in[0];
    const int* col1 = (const int*)d_in[2];
    const int* t1 = (const int*)d_in[3];
    const int* col2 = (const int*)d_in[5];
    const int* t2 = (const int*)d_in[6];
    const int* timep = (const int*)d_in[7];
    const int* intervalp = (const int*)d_in[8];
    const float* Ws1 = (const float*)d_in[9];
    const float* Wd1 = (const float*)d_in[10];
    const float* as1 = (const float*)d_in[11];
    const float* ad1 = (const float*)d_in[12];
    const float* b1 = (const float*)d_in[13];
    const float* g1 = (const float*)d_in[14];
    const float* beta1 = (const float*)d_in[15];
    const float* m1 = (const float*)d_in[16];
    const float* v1 = (const float*)d_in[17];
    const float* Ws2 = (const float*)d_in[18];
    const float* Wd2 = (const float*)d_in[19];
    const float* as2 = (const float*)d_in[20];
    const float* ad2 = (const float*)d_in[21];
    const float* b2 = (const float*)d_in[22];
    float* out = (float*)d_out;

    char* ws = (char*)d_ws;
    size_t off = 0;
    auto alloc = [&](size_t bytes) {
        size_t o = off;
        off += (bytes + 511) & ~(size_t)511;
        return o;
    };
    f16* hs = (f16*)(ws + alloc((size_t)N0C * 256 * 2));
    f16* h = (f16*)(ws + alloc((size_t)N1C * 256 * 2));
    f16* hs2 = (f16*)(ws + alloc((size_t)N1C * 128 * 2));
    float* a_s1 = (float*)(ws + alloc((size_t)N0C * 2 * 4));
    float* a_d1 = (float*)(ws + alloc((size_t)N1C * 2 * 4));
    float* a_s2 = (float*)(ws + alloc((size_t)N1C * 4));
    float* a_d2 = (float*)(ws + alloc((size_t)N2C * 4));
    f16* bfl1 = (f16*)(ws + alloc((size_t)73728 * 2));
    f16* bfl2 = (f16*)(ws + alloc((size_t)40960 * 2));
    float* e1 = (float*)(ws + alloc(1024 * 4));
    float* e2 = (float*)(ws + alloc(512 * 4));
    float* bns = (float*)(ws + alloc(256 * 4));
    float* bnt = (float*)(ws + alloc(256 * 4));

    prep1_kernel<<<256, 64, 0, stream>>>(Ws1, Wd1, as1, ad1, Ws2, Wd2, as2, ad2,
                                         b1, g1, beta1, m1, v1, e1, e2, bns, bnt);
    prep2_kernel<<<448, 256, 0, stream>>>(Ws1, Ws2, e1, e2, bfl1, bfl2);
    gemm1_kernel<<<dim3(2, 3125), 640, 0, stream>>>(x, bfl1, hs, a_s1, a_d1);
    agg1_kernel<<<N1C / 4, 256, 0, stream>>>(col1, t1, timep, intervalp,
                                             a_s1, a_d1, hs, bns, bnt, h);
    gemm2_kernel<<<(N1C + 127) / 128, 512, 0, stream>>>(h, bfl2, hs2, a_s2, a_d2);
    agg2_kernel<<<N2C / 4, 256, 0, stream>>>(col2, t2, timep, intervalp,
                                             a_s2, a_d2, hs2, b2, out);
}

// Round 12
// 102.704 us; speedup vs baseline: 1.0919x; 1.0919x over previous
//
#include <hip/hip_runtime.h>
#include <hip/hip_bf16.h>

#define N0C 100000
#define N1C 50000
#define N2C 25000

typedef _Float16 f16;
typedef _Float16 f16x2 __attribute__((ext_vector_type(2)));
typedef _Float16 f16x4 __attribute__((ext_vector_type(4)));
typedef _Float16 f16x8 __attribute__((ext_vector_type(8)));
typedef float f32x16 __attribute__((ext_vector_type(16)));

typedef const __attribute__((address_space(1))) unsigned int guint;
typedef __attribute__((address_space(3))) unsigned int luint;
__device__ __forceinline__ void gload16(const void* g, void* l) {
    __builtin_amdgcn_global_load_lds((guint*)g, (luint*)l, 16, 0, 0);
}

// ---------------------------------------------------------------- prep1 -----
__global__ void prep1_kernel(const float* __restrict__ Ws1, const float* __restrict__ Wd1,
                             const float* __restrict__ as1, const float* __restrict__ ad1,
                             const float* __restrict__ Ws2, const float* __restrict__ Wd2,
                             const float* __restrict__ as2, const float* __restrict__ ad2,
                             const float* __restrict__ b1, const float* __restrict__ g1,
                             const float* __restrict__ beta1, const float* __restrict__ m1,
                             const float* __restrict__ v1,
                             float* __restrict__ e1, float* __restrict__ e2,
                             float* __restrict__ bns, float* __restrict__ bnt) {
    int k = blockIdx.x, lane = threadIdx.x;
    float s0 = 0, s1 = 0, d0 = 0, d1 = 0, t0 = 0, t1 = 0;
    for (int c = lane; c < 128; c += 64) {
        s0 += Ws1[k * 256 + c] * as1[c];
        s1 += Ws1[k * 256 + 128 + c] * as1[128 + c];
        d0 += Wd1[k * 256 + c] * ad1[c];
        d1 += Wd1[k * 256 + 128 + c] * ad1[128 + c];
        t0 += Ws2[k * 128 + c] * as2[c];
        t1 += Wd2[k * 128 + c] * ad2[c];
    }
    for (int d = 1; d < 64; d <<= 1) {
        s0 += __shfl_xor(s0, d); s1 += __shfl_xor(s1, d);
        d0 += __shfl_xor(d0, d); d1 += __shfl_xor(d1, d);
        t0 += __shfl_xor(t0, d); t1 += __shfl_xor(t1, d);
    }
    if (lane == 0) {
        e1[k * 4 + 0] = s0; e1[k * 4 + 1] = s1; e1[k * 4 + 2] = d0; e1[k * 4 + 3] = d1;
        e2[k * 2 + 0] = t0; e2[k * 2 + 1] = t1;
        float sc = g1[k] * rsqrtf(v1[k] + 1e-5f);
        bns[k] = sc;
        bnt[k] = (b1[k] - m1[k]) * sc + beta1[k];
    }
}

// ---------------------------------------------------------------- prep2 -----
// bfl1: [9 nt][16 kb][64 lane][8 j]; bfl2: [5 nt][16 kb][64 lane][8 j]
// element (nt,kb,lane,j): n = nt*32 + (lane&31), k = kb*16 + (lane>>5)*8 + j
__global__ void prep2_kernel(const float* __restrict__ Ws1, const float* __restrict__ Ws2,
                             const float* __restrict__ e1, const float* __restrict__ e2,
                             f16* __restrict__ bfl1, f16* __restrict__ bfl2) {
    int i = blockIdx.x * 256 + threadIdx.x;
    if (i < 73728) {
        int j = i & 7, lane = (i >> 3) & 63, kb = (i >> 9) & 15, nt = i >> 13;
        int c = lane & 31, hi = lane >> 5;
        int k = kb * 16 + hi * 8 + j;
        float v;
        if (nt < 8) v = Ws1[k * 256 + nt * 32 + c];
        else v = (c < 4) ? e1[k * 4 + c] : 0.f;
        bfl1[i] = (f16)v;
    } else {
        int i2 = i - 73728;
        if (i2 < 40960) {
            int j = i2 & 7, lane = (i2 >> 3) & 63, kb = (i2 >> 9) & 15, nt = i2 >> 13;
            int c = lane & 31, hi = lane >> 5;
            int k = kb * 16 + hi * 8 + j;
            float v;
            if (nt < 4) v = Ws2[k * 128 + nt * 32 + c];
            else v = (c < 2) ? e2[k * 2 + c] : 0.f;
            bfl2[i2] = (f16)v;
        }
    }
}

// ---------------------------------------------------------------- gemm1 -----
// DMA-everything 2-phase. BM=128, BK=32, 8 steps, 8 waves (4 wr x 2 wg;
// wg0 = nt0-4, wg1 = nt5-8 incl. attention pad). A staged as RAW F32 via
// global_load_lds (zero registers, fire-and-forget, loads span the compute
// phase); f32->f16 conversion happens in the MFMA loop (idle VALU). A slots
// XOR-swizzled via pre-swizzled per-lane SOURCE (linear LDS dest, rule-21).
// slot s = row*8+gl holds x[row][ch*32 + (gl^(row&7))*4 ..+3] (4 f32 = 16B).
__global__ __launch_bounds__(512, 4) void gemm1_kernel(
    const float* __restrict__ x, const f16* __restrict__ bfl,
    f16* __restrict__ hs, float* __restrict__ as_out, float* __restrict__ ad_out) {
    __shared__ __align__(16) unsigned char smA[2][16384];
    __shared__ __align__(16) unsigned char smB[2][18432];
    const int t = threadIdx.x;
    const int wave = t >> 6, lane = t & 63;
    const int wr = wave & 3, wg = wave >> 2;
    const int col = lane & 31, hi = lane >> 5;
    const int r0 = blockIdx.x * 128;

    // per-thread A staging map (2 chunks of 16B)
    int arow[2], ag[2];
#pragma unroll
    for (int p = 0; p < 2; p++) {
        int s = (wave * 2 + p) * 64 + lane;
        int row = s >> 3;
        ag[p] = (s & 7) ^ (row & 7);
        int rc = r0 + row;
        arow[p] = rc > N0C - 1 ? N0C - 1 : rc;
    }

    // prologue: stage A(0) + B(0)
#pragma unroll
    for (int p = 0; p < 2; p++)
        gload16(x + (size_t)arow[p] * 256 + ag[p] * 4,
                smA[0] + ((wave * 2 + p) * 64 + lane) * 16);
    for (int c = wave; c < 18; c += 8) {
        int nt = c >> 1, kbl = c & 1;
        gload16(bfl + ((size_t)(nt * 16 + kbl) * 64 + lane) * 8, smB[0] + c * 1024 + lane * 16);
    }
    __syncthreads();

    f32x16 acc[5] = {};
    const int myrow = wr * 32 + col;
    const int m7 = myrow & 7;
    for (int ch = 0; ch < 8; ch++) {
        const int cur = ch & 1, nxt = cur ^ 1;
        const bool pre = ch < 7;
        if (pre) {  // fire-and-forget DMA staging for step ch+1
#pragma unroll
            for (int p = 0; p < 2; p++)
                gload16(x + (size_t)arow[p] * 256 + (ch + 1) * 32 + ag[p] * 4,
                        smA[nxt] + ((wave * 2 + p) * 64 + lane) * 16);
            for (int c = wave; c < 18; c += 8) {
                int nt = c >> 1, kbl = c & 1;
                gload16(bfl + ((size_t)(nt * 16 + (ch + 1) * 2 + kbl) * 64 + lane) * 8,
                        smB[nxt] + c * 1024 + lane * 16);
            }
        }
#pragma unroll
        for (int kb = 0; kb < 2; kb++) {
            int ob = kb * 4 + hi * 2;
            float4 fa = *(const float4*)(smA[cur] + (myrow * 8 + (ob ^ m7)) * 16);
            float4 fb = *(const float4*)(smA[cur] + (myrow * 8 + ((ob + 1) ^ m7)) * 16);
            f16x8 af = {(f16)fa.x, (f16)fa.y, (f16)fa.z, (f16)fa.w,
                        (f16)fb.x, (f16)fb.y, (f16)fb.z, (f16)fb.w};
            if (wg == 0) {
#pragma unroll
                for (int j = 0; j < 5; j++) {
                    f16x8 bf = *(const f16x8*)(smB[cur] + (j * 2 + kb) * 1024 + lane * 16);
                    acc[j] = __builtin_amdgcn_mfma_f32_32x32x16_f16(af, bf, acc[j], 0, 0, 0);
                }
            } else {
#pragma unroll
                for (int j = 0; j < 4; j++) {
                    f16x8 bf = *(const f16x8*)(smB[cur] + ((5 + j) * 2 + kb) * 1024 + lane * 16);
                    acc[j] = __builtin_amdgcn_mfma_f32_32x32x16_f16(af, bf, acc[j], 0, 0, 0);
                }
            }
        }
        __syncthreads();
    }

    // epilogue: C/D layout col=lane&31, row=(r&3)+8*(r>>2)+4*hi
    const int rbase = r0 + wr * 32 + 4 * hi;
    if (wg == 0) {
#pragma unroll
        for (int j = 0; j < 5; j++)
#pragma unroll
            for (int r = 0; r < 16; r++) {
                int grow = rbase + (r & 3) + 8 * (r >> 2);
                if (grow < N0C) hs[(size_t)grow * 256 + j * 32 + col] = (f16)acc[j][r];
            }
    } else {
#pragma unroll
        for (int j = 0; j < 3; j++)
#pragma unroll
            for (int r = 0; r < 16; r++) {
                int grow = rbase + (r & 3) + 8 * (r >> 2);
                if (grow < N0C) hs[(size_t)grow * 256 + (5 + j) * 32 + col] = (f16)acc[j][r];
            }
#pragma unroll
        for (int r = 0; r < 16; r++) {
            int grow = rbase + (r & 3) + 8 * (r >> 2);
            float v = acc[3][r];
            if (col < 2) {
                if (grow < N0C) as_out[grow * 2 + col] = v;
            } else if (col < 4) {
                if (grow < N1C) ad_out[grow * 2 + (col - 2)] = v;
            }
        }
    }
}

// ---------------------------------------------------------------- gemm2 -----
// R10's 2-phase skeleton (unchanged). A (f16) via global_load_lds with
// per-lane fragment-linear SOURCE; 8 A + 10 B chunks per step.
__global__ __launch_bounds__(512, 4) void gemm2_kernel(
    const f16* __restrict__ h, const f16* __restrict__ bfl,
    f16* __restrict__ hs2, float* __restrict__ as_out, float* __restrict__ ad_out) {
    __shared__ __align__(16) unsigned char smA[2][8192];
    __shared__ __align__(16) unsigned char smB[2][10240];
    const int t = threadIdx.x;
    const int wave = t >> 6, lane = t & 63;
    const int wr = wave & 3, wg = wave >> 2;
    const int col = lane & 31, hi = lane >> 5;
    const int r0 = blockIdx.x * 128;

    const int wrA = wave >> 1, kbA = wave & 1;
    int arowg = r0 + wrA * 32 + col;
    if (arowg > N1C - 1) arowg = N1C - 1;
    const f16* asrc = h + (size_t)arowg * 256 + kbA * 16 + hi * 8;

    gload16(asrc, smA[0] + wave * 1024 + lane * 16);
    for (int c = wave; c < 10; c += 8) {
        int nt = c >> 1, kbl = c & 1;
        gload16(bfl + ((size_t)(nt * 16 + kbl) * 64 + lane) * 8, smB[0] + c * 1024 + lane * 16);
    }
    __syncthreads();

    f32x16 acc[3] = {};
    for (int ch = 0; ch < 8; ch++) {
        const int cur = ch & 1, nxt = cur ^ 1;
        const bool pre = ch < 7;
        if (pre) {
            gload16(asrc + (ch + 1) * 32, smA[nxt] + wave * 1024 + lane * 16);
            for (int c = wave; c < 10; c += 8) {
                int nt = c >> 1, kbl = c & 1;
                gload16(bfl + ((size_t)(nt * 16 + (ch + 1) * 2 + kbl) * 64 + lane) * 8,
                        smB[nxt] + c * 1024 + lane * 16);
            }
        }
#pragma unroll
        for (int kb = 0; kb < 2; kb++) {
            f16x8 af = *(const f16x8*)(smA[cur] + ((wr * 2 + kb) * 64 + lane) * 16);
            if (wg == 0) {
#pragma unroll
                for (int j = 0; j < 3; j++) {
                    f16x8 bf = *(const f16x8*)(smB[cur] + (j * 2 + kb) * 1024 + lane * 16);
                    acc[j] = __builtin_amdgcn_mfma_f32_32x32x16_f16(af, bf, acc[j], 0, 0, 0);
                }
            } else {
#pragma unroll
                for (int j = 0; j < 2; j++) {
                    f16x8 bf = *(const f16x8*)(smB[cur] + ((3 + j) * 2 + kb) * 1024 + lane * 16);
                    acc[j] = __builtin_amdgcn_mfma_f32_32x32x16_f16(af, bf, acc[j], 0, 0, 0);
                }
            }
        }
        __syncthreads();
    }

    const int rbase = r0 + wr * 32 + 4 * hi;
    if (wg == 0) {
#pragma unroll
        for (int j = 0; j < 3; j++)
#pragma unroll
            for (int r = 0; r < 16; r++) {
                int grow = rbase + (r & 3) + 8 * (r >> 2);
                if (grow < N1C) hs2[(size_t)grow * 128 + j * 32 + col] = (f16)acc[j][r];
            }
    } else {
#pragma unroll
        for (int r = 0; r < 16; r++) {
            int grow = rbase + (r & 3) + 8 * (r >> 2);
            if (grow < N1C) hs2[(size_t)grow * 128 + 3 * 32 + col] = (f16)acc[0][r];
        }
#pragma unroll
        for (int r = 0; r < 16; r++) {
            int grow = rbase + (r & 3) + 8 * (r >> 2);
            float v = acc[1][r];
            if (col == 0) {
                if (grow < N1C) as_out[grow] = v;
            } else if (col == 1) {
                if (grow < N2C) ad_out[grow] = v;
            }
        }
    }
}

// ---------------------------------------------------------------- agg1 ------
__global__ void agg1_kernel(const int* __restrict__ col1, const int* __restrict__ t1,
                            const int* __restrict__ timep, const int* __restrict__ intervalp,
                            const float* __restrict__ a_s, const float* __restrict__ a_d,
                            const f16* __restrict__ hs,
                            const float* __restrict__ bns, const float* __restrict__ bnt,
                            f16* __restrict__ h) {
    int wid = (blockIdx.x * blockDim.x + threadIdx.x) >> 6;
    if (wid >= N1C) return;
    int lane = threadIdx.x & 63;
    int T = timep[0], I = intervalp[0];
    int j = lane & 15;
    int c = col1[wid * 16 + j];
    int tv = t1[wid * 16 + j];
    bool mk = (tv >= T) && (tv < T + I);
    float e0 = -INFINITY, e1 = -INFINITY;
    if (mk) {
        float s0 = a_s[c * 2 + 0] + a_d[wid * 2 + 0];
        float s1 = a_s[c * 2 + 1] + a_d[wid * 2 + 1];
        e0 = s0 > 0.f ? s0 : 0.2f * s0;
        e1 = s1 > 0.f ? s1 : 0.2f * s1;
    }
    float m0 = e0, m1 = e1;
#pragma unroll
    for (int d = 1; d < 16; d <<= 1) {
        m0 = fmaxf(m0, __shfl_xor(m0, d));
        m1 = fmaxf(m1, __shfl_xor(m1, d));
    }
    float ex0 = mk ? __expf(e0 - m0) : 0.f;
    float ex1 = mk ? __expf(e1 - m1) : 0.f;
    float s0 = ex0, s1 = ex1;
#pragma unroll
    for (int d = 1; d < 16; d <<= 1) {
        s0 += __shfl_xor(s0, d);
        s1 += __shfl_xor(s1, d);
    }
    float r0 = 1.f / fmaxf(s0, 1e-16f);
    float r1 = 1.f / fmaxf(s1, 1e-16f);
    unsigned long long mb = __ballot(mk) & 0xFFFFull;
    int head = lane >> 5;
    float rden = head ? r1 : r0;
    float acc0 = 0.f, acc1 = 0.f, acc2 = 0.f, acc3 = 0.f;
    while (mb) {
        int jj = __builtin_ctzll(mb);
        mb &= mb - 1;
        int cj = __shfl(c, jj);
        float w0 = __shfl(ex0, jj), w1 = __shfl(ex1, jj);
        float w = (head ? w1 : w0) * rden;
        f16x4 v = *(const f16x4*)(hs + (size_t)cj * 256 + lane * 4);
        acc0 += w * (float)v[0];
        acc1 += w * (float)v[1];
        acc2 += w * (float)v[2];
        acc3 += w * (float)v[3];
    }
    int cb = lane * 4;
    float4 sc = *(const float4*)(bns + cb);
    float4 sh = *(const float4*)(bnt + cb);
    float o0 = acc0 * sc.x + sh.x; o0 = o0 > 0.f ? o0 : 0.01f * o0;
    float o1 = acc1 * sc.y + sh.y; o1 = o1 > 0.f ? o1 : 0.01f * o1;
    float o2 = acc2 * sc.z + sh.z; o2 = o2 > 0.f ? o2 : 0.01f * o2;
    float o3 = acc3 * sc.w + sh.w; o3 = o3 > 0.f ? o3 : 0.01f * o3;
    f16x4 ov = {(f16)o0, (f16)o1, (f16)o2, (f16)o3};
    *(f16x4*)(h + (size_t)wid * 256 + cb) = ov;
}

// ---------------------------------------------------------------- agg2 ------
__global__ void agg2_kernel(const int* __restrict__ col2, const int* __restrict__ t2,
                            const int* __restrict__ timep, const int* __restrict__ intervalp,
                            const float* __restrict__ a_s, const float* __restrict__ a_d,
                            const f16* __restrict__ hs2,
                            const float* __restrict__ b2, float* __restrict__ out) {
    int wid = (blockIdx.x * blockDim.x + threadIdx.x) >> 6;
    if (wid >= N2C) return;
    int lane = threadIdx.x & 63;
    int T = timep[0], I = intervalp[0];
    int j = lane & 15;
    int c = col2[wid * 16 + j];
    int tv = t2[wid * 16 + j];
    bool mk = (tv >= T) && (tv < T + I);
    float e = -INFINITY;
    if (mk) {
        float s = a_s[c] + a_d[wid];
        e = s > 0.f ? s : 0.2f * s;
    }
    float m = e;
#pragma unroll
    for (int d = 1; d < 16; d <<= 1) m = fmaxf(m, __shfl_xor(m, d));
    float ex = mk ? __expf(e - m) : 0.f;
    float s = ex;
#pragma unroll
    for (int d = 1; d < 16; d <<= 1) s += __shfl_xor(s, d);
    float r = 1.f / fmaxf(s, 1e-16f);
    unsigned long long mb = __ballot(mk) & 0xFFFFull;
    float acc0 = 0.f, acc1 = 0.f;
    while (mb) {
        int jj = __builtin_ctzll(mb);
        mb &= mb - 1;
        int cj = __shfl(c, jj);
        float w = __shfl(ex, jj) * r;
        f16x2 v = *(const f16x2*)(hs2 + (size_t)cj * 128 + lane * 2);
        acc0 += w * (float)v[0];
        acc1 += w * (float)v[1];
    }
    float2 o = make_float2(acc0 + b2[lane * 2], acc1 + b2[lane * 2 + 1]);
    *(float2*)(out + (size_t)wid * 128 + lane * 2) = o;
}

// ---------------------------------------------------------------- launch ----
extern "C" void kernel_launch(void* const* d_in, const int* in_sizes, int n_in,
                              void* d_out, int out_size, void* d_ws, size_t ws_size,
                              hipStream_t stream) {
    const float* x = (const float*)d_in[0];
    const int* col1 = (const int*)d_in[2];
    const int* t1 = (const int*)d_in[3];
    const int* col2 = (const int*)d_in[5];
    const int* t2 = (const int*)d_in[6];
    const int* timep = (const int*)d_in[7];
    const int* intervalp = (const int*)d_in[8];
    const float* Ws1 = (const float*)d_in[9];
    const float* Wd1 = (const float*)d_in[10];
    const float* as1 = (const float*)d_in[11];
    const float* ad1 = (const float*)d_in[12];
    const float* b1 = (const float*)d_in[13];
    const float* g1 = (const float*)d_in[14];
    const float* beta1 = (const float*)d_in[15];
    const float* m1 = (const float*)d_in[16];
    const float* v1 = (const float*)d_in[17];
    const float* Ws2 = (const float*)d_in[18];
    const float* Wd2 = (const float*)d_in[19];
    const float* as2 = (const float*)d_in[20];
    const float* ad2 = (const float*)d_in[21];
    const float* b2 = (const float*)d_in[22];
    float* out = (float*)d_out;

    char* ws = (char*)d_ws;
    size_t off = 0;
    auto alloc = [&](size_t bytes) {
        size_t o = off;
        off += (bytes + 511) & ~(size_t)511;
        return o;
    };
    f16* hs = (f16*)(ws + alloc((size_t)N0C * 256 * 2));
    f16* h = (f16*)(ws + alloc((size_t)N1C * 256 * 2));
    f16* hs2 = (f16*)(ws + alloc((size_t)N1C * 128 * 2));
    float* a_s1 = (float*)(ws + alloc((size_t)N0C * 2 * 4));
    float* a_d1 = (float*)(ws + alloc((size_t)N1C * 2 * 4));
    float* a_s2 = (float*)(ws + alloc((size_t)N1C * 4));
    float* a_d2 = (float*)(ws + alloc((size_t)N2C * 4));
    f16* bfl1 = (f16*)(ws + alloc((size_t)73728 * 2));
    f16* bfl2 = (f16*)(ws + alloc((size_t)40960 * 2));
    float* e1 = (float*)(ws + alloc(1024 * 4));
    float* e2 = (float*)(ws + alloc(512 * 4));
    float* bns = (float*)(ws + alloc(256 * 4));
    float* bnt = (float*)(ws + alloc(256 * 4));

    prep1_kernel<<<256, 64, 0, stream>>>(Ws1, Wd1, as1, ad1, Ws2, Wd2, as2, ad2,
                                         b1, g1, beta1, m1, v1, e1, e2, bns, bnt);
    prep2_kernel<<<448, 256, 0, stream>>>(Ws1, Ws2, e1, e2, bfl1, bfl2);
    gemm1_kernel<<<(N0C + 127) / 128, 512, 0, stream>>>(x, bfl1, hs, a_s1, a_d1);
    agg1_kernel<<<N1C / 4, 256, 0, stream>>>(col1, t1, timep, intervalp,
                                             a_s1, a_d1, hs, bns, bnt, h);
    gemm2_kernel<<<(N1C + 127) / 128, 512, 0, stream>>>(h, bfl2, hs2, a_s2, a_d2);
    agg2_kernel<<<N2C / 4, 256, 0, stream>>>(col2, t2, timep, intervalp,
                                             a_s2, a_d2, hs2, b2, out);
}